// Round 2
// baseline (283.389 us; speedup 1.0000x reference)
//
#include <hip/hip_runtime.h>
#include <math.h>

#define D 1024
#define NH 8
#define HD 128
#define T 8193
#define NB 256
#define NT 1024

// ---- ws float-offsets ----
#define OFF_BAR    0         // 16 uints (zeroed by memset)
#define OFF_W      16        // 8192    (zeroed by memset; atomicAdd target)
#define OFF_QCLS   8208      // 1024
#define OFF_SC     9232      // 8*8193 = 65544
#define OFF_ML     74776     // 256*8*2 = 4096
#define OFF_U      78872     // 8192
#define OFF_ATT    87064     // 1024
#define OFF_CLS    88088     // 1024
#define OFF_PU     89112     // 256*8192 = 2097152

static __device__ __forceinline__ float wred(float v) {
    #pragma unroll
    for (int m = 32; m; m >>= 1) v += __shfl_xor(v, m, 64);
    return v;
}

static __device__ __forceinline__ void gbar(unsigned* bar, int idx) {
    __syncthreads();
    if (threadIdx.x == 0) {
        __threadfence();                       // release (agent scope, crosses XCD L2s)
        atomicAdd(&bar[idx], 1u);
        while (__hip_atomic_load(&bar[idx], __ATOMIC_ACQUIRE, __HIP_MEMORY_SCOPE_AGENT) < NB)
            __builtin_amdgcn_s_sleep(2);
        __threadfence();                       // acquire
    }
    __syncthreads();
}

__global__ __launch_bounds__(NT, 1) void fused_mhac(
    const float* __restrict__ x,  const float* __restrict__ ct,
    const float* __restrict__ Wq, const float* __restrict__ bq,
    const float* __restrict__ Wk, const float* __restrict__ bk,
    const float* __restrict__ Wv, const float* __restrict__ bv,
    const float* __restrict__ Wo, const float* __restrict__ bo,
    const float* __restrict__ Wc, const float* __restrict__ bc,
    float* __restrict__ out, float* __restrict__ ws)
{
    __shared__ float w_lds[NH * D];      // 32 KB, P3
    __shared__ float pl[NH][36];         // P5 probs tile
    __shared__ float mh[NH], rlh[NH];    // P4 result
    __shared__ float ch[NH];             // P3 bias dot
    __shared__ float red[32];            // generic wave-partial scratch
    __shared__ float wml[16][NH][2];     // P3 per-wave (m,l)
    __shared__ float red6[8][128];       // P6

    unsigned* bar = (unsigned*)ws;
    const int b = blockIdx.x, t = threadIdx.x;
    const int w = t >> 6, lane = t & 63;

    // ================= P1: qcls = Wq . ct + bq  (rows 4b..4b+3) =================
    {
        int grp = t >> 8;                 // wave-group -> row
        int f4  = t & 255;
        int r = b * 4 + grp;
        const float4* wr = (const float4*)(Wq + (size_t)r * D);
        const float4* cv = (const float4*)ct;
        float4 a = wr[f4], c = cv[f4];
        float v = a.x*c.x + a.y*c.y + a.z*c.z + a.w*c.w;
        v = wred(v);
        if (lane == 0) red[w] = v;
        __syncthreads();
        if (t < 4) {
            float s = red[4*t] + red[4*t+1] + red[4*t+2] + red[4*t+3];
            ws[OFF_QCLS + b*4 + t] = s + bq[b*4 + t];
        }
    }
    gbar(bar, 0);

    // ================= P2: w[h][j] = sum_d qcls_h[d] * Wk[h*HD+d][j] ============
    if (b < 64) {
        int h = b >> 3, seg = b & 7;      // 16 d-rows per block
        int j = t;
        float acc = 0.f;
        const float* base = Wk + ((size_t)(h*HD + seg*16)) * D + j;
        #pragma unroll
        for (int d = 0; d < 16; ++d) {
            float q = ws[OFF_QCLS + h*HD + seg*16 + d];
            acc += q * base[(size_t)d * D];
        }
        atomicAdd(&ws[OFF_W + h*D + j], acc);   // 8 contenders/address
    }
    gbar(bar, 1);

    // ================= P3: scores + per-block online (m,l) partials =============
    {
        float4* wl = (float4*)w_lds;
        const float4* wg = (const float4*)(ws + OFF_W);
        wl[t] = wg[t];
        wl[t + 1024] = wg[t + 1024];
        {   // ch[h] = qcls_h . bk_h
            int h = t >> 7, d = t & 127;
            float v = ws[OFF_QCLS + h*HD + d] * bk[h*HD + d];
            v = wred(v);
            if (lane == 0) red[w] = v;
        }
        __syncthreads();
        if (t < 8) ch[t] = red[2*t] + red[2*t+1];
        __syncthreads();

        float mw[8], lw[8];
        #pragma unroll
        for (int h = 0; h < 8; ++h) { mw[h] = -1e30f; lw[h] = 0.f; }
        const float scale = 0.08838834764831845f;
        int gw = b * 16 + w;              // 0..4095
        for (int it = 0; it < 3; ++it) {
            int s = gw + it * 4096;
            if (s >= T) break;
            const float4* tok = (const float4*)((s == 0) ? ct : (x + (size_t)(s-1) * D));
            float4 t0 = tok[lane], t1 = tok[lane+64], t2 = tok[lane+128], t3 = tok[lane+192];
            #pragma unroll
            for (int h = 0; h < 8; ++h) {
                const float4* wh = (const float4*)(w_lds + h*D);
                float4 a0 = wh[lane], a1 = wh[lane+64], a2 = wh[lane+128], a3 = wh[lane+192];
                float v = a0.x*t0.x + a0.y*t0.y + a0.z*t0.z + a0.w*t0.w
                        + a1.x*t1.x + a1.y*t1.y + a1.z*t1.z + a1.w*t1.w
                        + a2.x*t2.x + a2.y*t2.y + a2.z*t2.z + a2.w*t2.w
                        + a3.x*t3.x + a3.y*t3.y + a3.z*t3.z + a3.w*t3.w;
                v = wred(v);
                float sc = scale * (v + ch[h]);
                if (lane == 0) ws[OFF_SC + h*T + s] = sc;
                float mn = fmaxf(mw[h], sc);
                lw[h] = lw[h] * __expf(mw[h] - mn) + __expf(sc - mn);
                mw[h] = mn;
            }
        }
        if (lane == 0) {
            #pragma unroll
            for (int h = 0; h < 8; ++h) { wml[w][h][0] = mw[h]; wml[w][h][1] = lw[h]; }
        }
        __syncthreads();
        if (t < 64) {
            int h = lane & 7, wseg = lane >> 3;
            float m0 = wml[2*wseg][h][0],   l0 = wml[2*wseg][h][1];
            float m1 = wml[2*wseg+1][h][0], l1 = wml[2*wseg+1][h][1];
            float mm = fmaxf(m0, m1);
            float ll = l0*__expf(m0-mm) + l1*__expf(m1-mm);
            #pragma unroll
            for (int d = 8; d < 64; d <<= 1) {
                float om = __shfl_xor(mm, d, 64);
                float ol = __shfl_xor(ll, d, 64);
                float nm = fmaxf(mm, om);
                ll = ll*__expf(mm-nm) + ol*__expf(om-nm);
                mm = nm;
            }
            if (lane < 8) {
                ws[OFF_ML + b*16 + 2*h]     = mm;
                ws[OFF_ML + b*16 + 2*h + 1] = ll;
            }
        }
    }
    gbar(bar, 2);

    // ================= P4: combine (m,l) partials — redundant per block =========
    {
        if (t < 256) {
            int h = t >> 5, i = t & 31;
            float mm = -1e30f, ll = 0.f;
            for (int pb = i; pb < 256; pb += 32) {
                float m2 = ws[OFF_ML + pb*16 + 2*h];
                float l2 = ws[OFF_ML + pb*16 + 2*h + 1];
                float nm = fmaxf(mm, m2);
                ll = ll*__expf(mm-nm) + l2*__expf(m2-nm);
                mm = nm;
            }
            #pragma unroll
            for (int d = 1; d < 32; d <<= 1) {
                float om = __shfl_xor(mm, d, 64);
                float ol = __shfl_xor(ll, d, 64);
                float nm = fmaxf(mm, om);
                ll = ll*__expf(mm-nm) + ol*__expf(om-nm);
                mm = nm;
            }
            if ((t & 31) == 0) { mh[h] = mm; rlh[h] = 1.f / ll; }
        }
        __syncthreads();
    }

    // ================= P5: probs -> A, u-partials (32/33 tokens per block) ======
    {
        int start = b * 32;
        int nt_ = (b == 255) ? 33 : 32;
        if (t < 256) {
            int h = t >> 5, k = t & 31;
            pl[h][k] = __expf(ws[OFF_SC + h*T + start + k] - mh[h]) * rlh[h];
        } else if (t >= 256 && t < 264 && nt_ == 33) {
            int h = t - 256;
            pl[h][32] = __expf(ws[OFF_SC + h*T + start + 32] - mh[h]) * rlh[h];
        }
        __syncthreads();
        if (t < nt_) {
            int s = start + t;
            if (s >= 1) {
                float sum = 0.f;
                #pragma unroll
                for (int h = 0; h < 8; ++h) sum += pl[h][t];
                out[7 + s - 1] = sum * 0.125f;
            }
        }
        int f4 = t >> 2, hp = t & 3;
        float4 a0 = {0,0,0,0}, a1 = {0,0,0,0};
        for (int k = 0; k < nt_; ++k) {
            int s = start + k;
            const float4* tok = (const float4*)((s == 0) ? ct : (x + (size_t)(s-1) * D));
            float4 tv = tok[f4];
            float p0 = pl[2*hp][k], p1 = pl[2*hp+1][k];
            a0.x += p0*tv.x; a0.y += p0*tv.y; a0.z += p0*tv.z; a0.w += p0*tv.w;
            a1.x += p1*tv.x; a1.y += p1*tv.y; a1.z += p1*tv.z; a1.w += p1*tv.w;
        }
        float4* pu = (float4*)(ws + OFF_PU + (size_t)b * 8192);
        pu[(2*hp)*256 + f4]   = a0;
        pu[(2*hp+1)*256 + f4] = a1;
    }
    gbar(bar, 3);

    // ================= P6: u = sum over 256 chunks of part_u ====================
    if (b < 64) {
        int sub = t >> 7, ol = t & 127;
        int o = b * 128 + ol;
        float acc = 0.f;
        for (int c = sub*32; c < sub*32 + 32; ++c)
            acc += ws[OFF_PU + (size_t)c * 8192 + o];
        red6[sub][ol] = acc;
        __syncthreads();
        if (t < 128) {
            float s2 = 0.f;
            #pragma unroll
            for (int i2 = 0; i2 < 8; ++i2) s2 += red6[i2][t];
            ws[OFF_U + b*128 + t] = s2;
        }
    }
    gbar(bar, 4);

    // ================= P7: attn_out = Wv . u_head + bv ==========================
    if (b < 64) {
        int r = b*16 + w;
        int h = r >> 7;
        const float4* wr = (const float4*)(Wv + (size_t)r * D);
        const float4* uu = (const float4*)(ws + OFF_U + h*D);
        float v = 0.f;
        #pragma unroll
        for (int i2 = 0; i2 < 4; ++i2) {
            float4 a = wr[i2*64 + lane], c = uu[i2*64 + lane];
            v += a.x*c.x + a.y*c.y + a.z*c.z + a.w*c.w;
        }
        v = wred(v);
        if (lane == 0) ws[OFF_ATT + r] = v + bv[r];
    }
    gbar(bar, 5);

    // ================= P8: cls_out = Wo . attn_out + bo =========================
    if (b < 64) {
        int r = b*16 + w;
        const float4* wr = (const float4*)(Wo + (size_t)r * D);
        const float4* av = (const float4*)(ws + OFF_ATT);
        float v = 0.f;
        #pragma unroll
        for (int i2 = 0; i2 < 4; ++i2) {
            float4 a = wr[i2*64 + lane], c = av[i2*64 + lane];
            v += a.x*c.x + a.y*c.y + a.z*c.z + a.w*c.w;
        }
        v = wred(v);
        if (lane == 0) ws[OFF_CLS + r] = v + bo[r];
    }
    gbar(bar, 6);

    // ================= P9: logits / softmax / outputs ===========================
    if (b == 0) {
        float c = ws[OFF_CLS + t];
        float v0 = Wc[t] * c;
        float v1 = Wc[D + t] * c;
        v0 = wred(v0); v1 = wred(v1);
        if (lane == 0) { red[w] = v0; red[16 + w] = v1; }
        __syncthreads();
        if (t == 0) {
            float a0 = 0.f, a1 = 0.f;
            #pragma unroll
            for (int i2 = 0; i2 < 16; ++i2) { a0 += red[i2]; a1 += red[16 + i2]; }
            float l0 = a0 + bc[0], l1 = a1 + bc[1];
            float mx = fmaxf(l0, l1);
            float e0 = __expf(l0 - mx), e1 = __expf(l1 - mx);
            float inv = 1.f / (e0 + e1);
            float p0 = e0 * inv, p1 = e1 * inv;
            int am = (p1 > p0) ? 1 : 0;
            out[0] = l0; out[1] = l1;
            out[2] = p0; out[3] = p1;
            out[4] = (float)am;
            out[5] = p0; out[6] = p1;
        }
    }
}

extern "C" void kernel_launch(void* const* d_in, const int* in_sizes, int n_in,
                              void* d_out, int out_size, void* d_ws, size_t ws_size,
                              hipStream_t stream) {
    const float* x  = (const float*)d_in[0];
    const float* ct = (const float*)d_in[1];
    const float* Wq = (const float*)d_in[2];
    const float* bq = (const float*)d_in[3];
    const float* Wk = (const float*)d_in[4];
    const float* bk = (const float*)d_in[5];
    const float* Wv = (const float*)d_in[6];
    const float* bv = (const float*)d_in[7];
    const float* Wo = (const float*)d_in[8];
    const float* bo = (const float*)d_in[9];
    const float* Wc = (const float*)d_in[10];
    const float* bc = (const float*)d_in[11];
    float* out = (float*)d_out;
    float* ws  = (float*)d_ws;

    // zero barrier counters + w accumulator (graph-capturable memset node)
    hipMemsetAsync(d_ws, 0, (OFF_W + 8192) * sizeof(float), stream);
    fused_mhac<<<dim3(NB), dim3(NT), 0, stream>>>(x, ct, Wq, bq, Wk, bk, Wv, bv,
                                                  Wo, bo, Wc, bc, out, ws);
}

// Round 3
// 167.302 us; speedup vs baseline: 1.6939x; 1.6939x over previous
//
#include <hip/hip_runtime.h>
#include <math.h>

#define D 1024
#define NH 8
#define HD 128
#define T 8193

// ---- ws float-offsets ----
// zeroed region (memset before K1):
#define OFF_LOGITS 0          // 2
#define OFF_DONE   2          // 1 uint (+1 pad)
#define OFF_E      4          // 2048   E[c*1024+r]
#define OFF_G      2052       // 16384  G[c*8192 + h*1024 + j]
#define OFF_W      18436      // 8192   w[h*1024+j]
#define ZERO_FLTS  26628
// written-before-read region:
#define OFF_QCLS   26628      // 1024
#define OFF_CH     27652      // 8
#define OFF_CONST  27660      // 4 (2 used)
#define OFF_SC     27664      // 8*8193 = 65544
#define OFF_ML     93208      // 256*16 = 4096   ml[b*16 + 2h] = m, +1 = l
#define OFF_UB     97304      // 256*8192        u_b[b][h*1024+j]
#define OFF_U      2194456    // 8192 final u (normalized)

static __device__ __forceinline__ float wred(float v) {
    #pragma unroll
    for (int m = 32; m; m >>= 1) v += __shfl_xor(v, m, 64);
    return v;
}

// ============ K1: qcls (blocks 0..1023) + E = Wc.Wo (blocks 1024..1087) ======
__global__ __launch_bounds__(256) void k1(const float* __restrict__ Wq,
                                          const float* __restrict__ bq,
                                          const float* __restrict__ ct,
                                          const float* __restrict__ Wc,
                                          const float* __restrict__ Wo,
                                          float* __restrict__ ws) {
    __shared__ float red[4];
    int b = blockIdx.x, t = threadIdx.x;
    if (b < 1024) {                       // qcls[b] = Wq[b,:].ct + bq[b]
        const float4* wr = (const float4*)(Wq + (size_t)b * D);
        const float4* cv = (const float4*)ct;
        float4 a = wr[t], c = cv[t];
        float v = a.x*c.x + a.y*c.y + a.z*c.z + a.w*c.w;
        v = wred(v);
        if ((t & 63) == 0) red[t >> 6] = v;
        __syncthreads();
        if (t == 0) ws[OFF_QCLS + b] = red[0]+red[1]+red[2]+red[3] + bq[b];
    } else {                              // E[c,:] partial over 32 Wo rows
        int idx = b - 1024;               // 0..63
        int c = idx >> 5, i0 = (idx & 31) * 32;
        const float4* Wo4 = (const float4*)Wo;
        float4 acc = {0,0,0,0};
        #pragma unroll 8
        for (int i = 0; i < 32; ++i) {
            float s = Wc[c * D + i0 + i];
            float4 r = Wo4[(size_t)(i0 + i) * 256 + t];
            acc.x += s*r.x; acc.y += s*r.y; acc.z += s*r.z; acc.w += s*r.w;
        }
        float* e = ws + OFF_E + c * D + t * 4;
        atomicAdd(e+0, acc.x); atomicAdd(e+1, acc.y);
        atomicAdd(e+2, acc.z); atomicAdd(e+3, acc.w);
    }
}

// ============ K2: w (0..63) + G (64..191) + ch (192) + const (193) ===========
__global__ __launch_bounds__(1024) void k2(const float* __restrict__ Wk,
                                           const float* __restrict__ bk,
                                           const float* __restrict__ Wv,
                                           const float* __restrict__ Wc,
                                           const float* __restrict__ bo,
                                           const float* __restrict__ bv,
                                           const float* __restrict__ bc,
                                           float* __restrict__ ws) {
    int b = blockIdx.x, t = threadIdx.x;
    int w = t >> 6, lane = t & 63;
    if (b < 64) {                         // w[h,j] partial over 16 d-rows
        int h = b >> 3, seg = b & 7;
        float acc = 0.f;
        const float* base = Wk + ((size_t)(h*HD + seg*16)) * D + t;
        #pragma unroll
        for (int d = 0; d < 16; ++d)
            acc += ws[OFF_QCLS + h*HD + seg*16 + d] * base[(size_t)d * D];
        atomicAdd(&ws[OFF_W + h*D + t], acc);
    } else if (b < 192) {                 // G[c,h,:] partial
        __shared__ float4 gred[4][256];
        int idx = b - 64;                 // 0..127
        int c = idx >> 6, h = (idx >> 3) & 7, rseg = idx & 7;
        int j4 = t & 255, rsub = t >> 8;
        int r0 = h*HD + rseg*16 + rsub*4;
        const float4* Wv4 = (const float4*)Wv;
        float4 acc = {0,0,0,0};
        #pragma unroll
        for (int r = 0; r < 4; ++r) {
            float s = ws[OFF_E + c*D + r0 + r];
            float4 v = Wv4[(size_t)(r0 + r) * 256 + j4];
            acc.x += s*v.x; acc.y += s*v.y; acc.z += s*v.z; acc.w += s*v.w;
        }
        gred[rsub][j4] = acc;
        __syncthreads();
        if (rsub == 0) {
            float4 a0 = gred[0][j4], a1 = gred[1][j4], a2 = gred[2][j4], a3 = gred[3][j4];
            float* g = ws + OFF_G + c*8192 + h*D + j4*4;
            atomicAdd(g+0, a0.x+a1.x+a2.x+a3.x);
            atomicAdd(g+1, a0.y+a1.y+a2.y+a3.y);
            atomicAdd(g+2, a0.z+a1.z+a2.z+a3.z);
            atomicAdd(g+3, a0.w+a1.w+a2.w+a3.w);
        }
    } else if (b == 192) {                // ch[h] = qcls_h . bk_h
        __shared__ float red[16];
        int h = t >> 7, d = t & 127;
        float v = ws[OFF_QCLS + h*HD + d] * bk[h*HD + d];
        v = wred(v);
        if (lane == 0) red[w] = v;
        __syncthreads();
        if (t < 8) ws[OFF_CH + t] = red[2*t] + red[2*t+1];
    } else {                              // const_c = Wc.bo + E.bv + bc
        __shared__ float red[32];
        float v0 = Wc[t]*bo[t] + ws[OFF_E + t]*bv[t];
        float v1 = Wc[D + t]*bo[t] + ws[OFF_E + D + t]*bv[t];
        v0 = wred(v0); v1 = wred(v1);
        if (lane == 0) { red[w] = v0; red[16 + w] = v1; }
        __syncthreads();
        if (t == 0) {
            float a0 = 0.f, a1 = 0.f;
            #pragma unroll
            for (int i = 0; i < 16; ++i) { a0 += red[i]; a1 += red[16+i]; }
            ws[OFF_CONST + 0] = a0 + bc[0];
            ws[OFF_CONST + 1] = a1 + bc[1];
        }
    }
}

// ============ K3: scores + block-local (m_b, l_b, u_b)  (grid 256 x 1024) ====
__global__ __launch_bounds__(1024) void k3(const float* __restrict__ x,
                                           const float* __restrict__ ct,
                                           float* __restrict__ ws) {
    __shared__ float wlds[NH * D];        // 32 KB
    __shared__ float chs[NH];
    __shared__ float scl[NH][33];
    __shared__ float mbs[NH], lbs[NH];
    int b = blockIdx.x, t = threadIdx.x;
    int w = t >> 6, lane = t & 63;

    float4* wl4 = (float4*)wlds;
    const float4* wg4 = (const float4*)(ws + OFF_W);
    wl4[t] = wg4[t];
    wl4[t + 1024] = wg4[t + 1024];
    if (t < 8) chs[t] = ws[OFF_CH + t];
    __syncthreads();

    int nt_ = (b == 255) ? 33 : 32;
    // ---- stage A: scores for this block's tokens (2 per wave, +1 tail) ----
    {
        const float scale = 0.08838834764831845f;
        int nw = 2 + ((b == 255 && w == 15) ? 1 : 0);
        for (int it = 0; it < nw; ++it) {
            int k = (it < 2) ? (w*2 + it) : 32;
            int s = b*32 + k;
            const float4* tok = (const float4*)((s == 0) ? ct : (x + (size_t)(s-1) * D));
            float4 t0 = tok[lane], t1 = tok[lane+64], t2 = tok[lane+128], t3 = tok[lane+192];
            #pragma unroll
            for (int h = 0; h < 8; ++h) {
                const float4* wh = (const float4*)(wlds + h*D);
                float4 a0 = wh[lane], a1 = wh[lane+64], a2 = wh[lane+128], a3 = wh[lane+192];
                float v = a0.x*t0.x + a0.y*t0.y + a0.z*t0.z + a0.w*t0.w
                        + a1.x*t1.x + a1.y*t1.y + a1.z*t1.z + a1.w*t1.w
                        + a2.x*t2.x + a2.y*t2.y + a2.z*t2.z + a2.w*t2.w
                        + a3.x*t3.x + a3.y*t3.y + a3.z*t3.z + a3.w*t3.w;
                v = wred(v);
                if (lane == 0) {
                    float sc = scale * (v + chs[h]);
                    ws[OFF_SC + (size_t)h*T + s] = sc;
                    scl[h][k] = sc;
                }
            }
        }
    }
    __syncthreads();
    // ---- stage B: per-block per-head (m_b, l_b) ----
    if (t < 8) {
        float m = -1e30f;
        for (int k = 0; k < nt_; ++k) m = fmaxf(m, scl[t][k]);
        float l = 0.f;
        for (int k = 0; k < nt_; ++k) l += __expf(scl[t][k] - m);
        mbs[t] = m; lbs[t] = l;
        ws[OFF_ML + b*16 + 2*t]     = m;
        ws[OFF_ML + b*16 + 2*t + 1] = l;
    }
    __syncthreads();
    // ---- stage C: u_b[h,:] = sum_k e^{sc-m_b} * tok_k  (L2-hot re-read) ----
    {
        int f4 = t >> 2, hp = t & 3;
        int h0 = 2*hp, h1 = h0 + 1;
        float m0 = mbs[h0], m1 = mbs[h1];
        float4 a0 = {0,0,0,0}, a1 = {0,0,0,0};
        for (int k = 0; k < nt_; ++k) {
            int s = b*32 + k;
            const float4* tok = (const float4*)((s == 0) ? ct : (x + (size_t)(s-1) * D));
            float4 tv = tok[f4];
            float p0 = __expf(scl[h0][k] - m0);
            float p1 = __expf(scl[h1][k] - m1);
            a0.x += p0*tv.x; a0.y += p0*tv.y; a0.z += p0*tv.z; a0.w += p0*tv.w;
            a1.x += p1*tv.x; a1.y += p1*tv.y; a1.z += p1*tv.z; a1.w += p1*tv.w;
        }
        float4* pu = (float4*)(ws + OFF_UB + (size_t)b * 8192);
        pu[h0*256 + f4] = a0;
        pu[h1*256 + f4] = a1;
    }
}

// ============ K4: stats combine + u-reduce + A + logits + finalize ===========
__global__ __launch_bounds__(1024) void k4(const float* __restrict__ x,
                                           float* __restrict__ out,
                                           float* __restrict__ ws) {
    __shared__ float mh[NH], rlh[NH];
    __shared__ float scale[256];
    __shared__ float red6[8][128];
    __shared__ float red[32];
    int b = blockIdx.x, t = threadIdx.x;
    int w = t >> 6, lane = t & 63;

    // ---- stage 1 (all blocks): global (m_h, 1/l_h) from 256 partials ----
    if (t < 256) {
        int h = t >> 5, i = t & 31;
        float mm = -1e30f, ll = 0.f;
        for (int pb = i; pb < 256; pb += 32) {
            float m2 = ws[OFF_ML + pb*16 + 2*h];
            float l2 = ws[OFF_ML + pb*16 + 2*h + 1];
            float nm = fmaxf(mm, m2);
            ll = ll*__expf(mm-nm) + l2*__expf(m2-nm);
            mm = nm;
        }
        #pragma unroll
        for (int d = 1; d < 32; d <<= 1) {
            float om = __shfl_xor(mm, d, 64);
            float ol = __shfl_xor(ll, d, 64);
            float nm = fmaxf(mm, om);
            ll = ll*__expf(mm-nm) + ol*__expf(om-nm);
            mm = nm;
        }
        if ((t & 31) == 0) { mh[h] = mm; rlh[h] = 1.f / ll; }
    }
    __syncthreads();

    if (b < 64) {
        // ---- u-reduce: 128 consecutive u elements (one head) ----
        int h = b >> 3;
        if (t < 256) scale[t] = __expf(ws[OFF_ML + t*16 + 2*h] - mh[h]);
        __syncthreads();
        int j = t & 127, seg = t >> 7;
        float acc = 0.f;
        for (int pb = seg*32; pb < seg*32 + 32; ++pb)
            acc += scale[pb] * ws[OFF_UB + (size_t)pb * 8192 + b*128 + j];
        red6[seg][j] = acc;
        __syncthreads();
        float uval = 0.f;
        if (t < 128) {
            #pragma unroll
            for (int s2 = 0; s2 < 8; ++s2) uval += red6[s2][t];
            uval *= rlh[h];
            ws[OFF_U + b*128 + t] = uval;
        }
        // ---- logits contribution: G[c,h,jglob] . u_slice ----
        float v0 = 0.f, v1 = 0.f;
        if (t < 128) {
            int jg = b*128 + t;
            v0 = ws[OFF_G + jg] * uval;
            v1 = ws[OFF_G + 8192 + jg] * uval;
        }
        v0 = wred(v0); v1 = wred(v1);
        if (lane == 0 && w < 2) { red[w] = v0; red[16 + w] = v1; }
        __syncthreads();
        if (t == 0) {
            atomicAdd(&ws[OFF_LOGITS + 0], red[0] + red[1]);
            atomicAdd(&ws[OFF_LOGITS + 1], red[16] + red[17]);
            __threadfence();
            unsigned old = atomicAdd((unsigned*)(ws + OFF_DONE), 1u);
            if (old == 63) {              // last u-block finalizes
                float l0 = atomicAdd(&ws[OFF_LOGITS + 0], 0.f) + ws[OFF_CONST + 0];
                float l1 = atomicAdd(&ws[OFF_LOGITS + 1], 0.f) + ws[OFF_CONST + 1];
                float mx = fmaxf(l0, l1);
                float e0 = __expf(l0 - mx), e1 = __expf(l1 - mx);
                float inv = 1.f / (e0 + e1);
                float p0 = e0 * inv, p1 = e1 * inv;
                int am = (p1 > p0) ? 1 : 0;
                out[0] = l0; out[1] = l1;
                out[2] = p0; out[3] = p1;
                out[4] = (float)am;
                out[5] = p0; out[6] = p1;
            }
        }
    } else {
        // ---- A[s] = (1/8) sum_h e^{sc-m_h}/l_h,  s in 1..8192 ----
        int idx = b - 64;                 // 0..191
        int s0 = 1 + idx * 43;
        int cnt = 8193 - s0; if (cnt > 43) cnt = 43;
        if (cnt > 0 && t < cnt) {
            int s = s0 + t;
            float sum = 0.f;
            #pragma unroll
            for (int h = 0; h < 8; ++h)
                sum += __expf(ws[OFF_SC + (size_t)h*T + s] - mh[h]) * rlh[h];
            out[7 + s - 1] = sum * 0.125f;
        }
    }
}

extern "C" void kernel_launch(void* const* d_in, const int* in_sizes, int n_in,
                              void* d_out, int out_size, void* d_ws, size_t ws_size,
                              hipStream_t stream) {
    const float* x  = (const float*)d_in[0];
    const float* ct = (const float*)d_in[1];
    const float* Wq = (const float*)d_in[2];
    const float* bq = (const float*)d_in[3];
    const float* Wk = (const float*)d_in[4];
    const float* bk = (const float*)d_in[5];
    const float* Wv = (const float*)d_in[6];
    const float* bv = (const float*)d_in[7];
    const float* Wo = (const float*)d_in[8];
    const float* bo = (const float*)d_in[9];
    const float* Wc = (const float*)d_in[10];
    const float* bc = (const float*)d_in[11];
    float* out = (float*)d_out;
    float* ws  = (float*)d_ws;

    hipMemsetAsync(d_ws, 0, ZERO_FLTS * sizeof(float), stream);
    k1<<<dim3(1088), dim3(256),  0, stream>>>(Wq, bq, ct, Wc, Wo, ws);
    k2<<<dim3(194),  dim3(1024), 0, stream>>>(Wk, bk, Wv, Wc, bo, bv, bc, ws);
    k3<<<dim3(256),  dim3(1024), 0, stream>>>(x, ct, ws);
    k4<<<dim3(256),  dim3(1024), 0, stream>>>(x, out, ws);
}

// Round 4
// 135.942 us; speedup vs baseline: 2.0846x; 1.2307x over previous
//
#include <hip/hip_runtime.h>
#include <math.h>

#define D 1024
#define NH 8
#define T 8193

// ---- ws float-offsets ----
// zeroed region (memset before K1):
#define OFF_LOGITS 0          // 2
#define OFF_DONE   2          // 1 uint (+1 pad)
#define OFF_E      4          // 2048   E[c*1024+r]
#define OFF_G      2052       // 16384  G[c*8192 + h*1024 + j]
#define OFF_W      18436      // 8192   w[h*1024+j]
#define ZERO_FLTS  26628
// written-before-read region:
#define OFF_QCLS   26628      // 1024
#define OFF_CH     27652      // 8
#define OFF_CONST  27660      // 4 (2 used)
#define OFF_L      27664      // 256*8 = 2048   l_b per block per head
#define OFF_SCT    29712      // 8193*8 = 65544 scores transposed [s][h]
#define OFF_UB     95256      // 256*8192       u_b[b][h*1024+j]

static __device__ __forceinline__ float wred(float v) {
    #pragma unroll
    for (int m = 32; m; m >>= 1) v += __shfl_xor(v, m, 64);
    return v;
}

// DPP wave-64 sum: result broadcast via readlane(63). VALU-pipe only.
#define DPPADD(v, ctrl) \
    ((v) + __int_as_float(__builtin_amdgcn_update_dpp( \
        0, __float_as_int(v), (ctrl), 0xf, 0xf, true)))

static __device__ __forceinline__ float wave_total(float v) {
    v = DPPADD(v, 0x111);   // row_shr:1
    v = DPPADD(v, 0x112);   // row_shr:2
    v = DPPADD(v, 0x114);   // row_shr:4
    v = DPPADD(v, 0x118);   // row_shr:8
    v = DPPADD(v, 0x142);   // row_bcast:15
    v = DPPADD(v, 0x143);   // row_bcast:31
    return __int_as_float(__builtin_amdgcn_readlane(__float_as_int(v), 63));
}

// ============ K1: qcls (blocks 0..1023) + E = Wc.Wo (blocks 1024..1087) ======
__global__ __launch_bounds__(256) void k1(const float* __restrict__ Wq,
                                          const float* __restrict__ bq,
                                          const float* __restrict__ ct,
                                          const float* __restrict__ Wc,
                                          const float* __restrict__ Wo,
                                          float* __restrict__ ws) {
    __shared__ float red[4];
    int b = blockIdx.x, t = threadIdx.x;
    if (b < 1024) {                       // qcls[b] = Wq[b,:].ct + bq[b]
        const float4* wr = (const float4*)(Wq + (size_t)b * D);
        const float4* cv = (const float4*)ct;
        float4 a = wr[t], c = cv[t];
        float v = a.x*c.x + a.y*c.y + a.z*c.z + a.w*c.w;
        v = wred(v);
        if ((t & 63) == 0) red[t >> 6] = v;
        __syncthreads();
        if (t == 0) ws[OFF_QCLS + b] = red[0]+red[1]+red[2]+red[3] + bq[b];
    } else {                              // E[c,:] partial over 32 Wo rows
        int idx = b - 1024;               // 0..63
        int c = idx >> 5, i0 = (idx & 31) * 32;
        const float4* Wo4 = (const float4*)Wo;
        float4 acc = {0,0,0,0};
        #pragma unroll 8
        for (int i = 0; i < 32; ++i) {
            float s = Wc[c * D + i0 + i];
            float4 r = Wo4[(size_t)(i0 + i) * 256 + t];
            acc.x += s*r.x; acc.y += s*r.y; acc.z += s*r.z; acc.w += s*r.w;
        }
        float* e = ws + OFF_E + c * D + t * 4;
        atomicAdd(e+0, acc.x); atomicAdd(e+1, acc.y);
        atomicAdd(e+2, acc.z); atomicAdd(e+3, acc.w);
    }
}

// ============ K2: w (0..63) + G (64..191) + ch (192) + const (193) ===========
__global__ __launch_bounds__(1024) void k2(const float* __restrict__ Wk,
                                           const float* __restrict__ bk,
                                           const float* __restrict__ Wv,
                                           const float* __restrict__ Wc,
                                           const float* __restrict__ bo,
                                           const float* __restrict__ bv,
                                           const float* __restrict__ bc,
                                           float* __restrict__ ws) {
    int b = blockIdx.x, t = threadIdx.x;
    int w = t >> 6, lane = t & 63;
    if (b < 64) {                         // w[h,j] partial over 16 d-rows
        int h = b >> 3, seg = b & 7;
        float acc = 0.f;
        const float* base = Wk + ((size_t)(h*128 + seg*16)) * D + t;
        #pragma unroll
        for (int d = 0; d < 16; ++d)
            acc += ws[OFF_QCLS + h*128 + seg*16 + d] * base[(size_t)d * D];
        atomicAdd(&ws[OFF_W + h*D + t], acc);
    } else if (b < 192) {                 // G[c,h,:] partial
        __shared__ float4 gred[4][256];
        int idx = b - 64;                 // 0..127
        int c = idx >> 6, h = (idx >> 3) & 7, rseg = idx & 7;
        int j4 = t & 255, rsub = t >> 8;
        int r0 = h*128 + rseg*16 + rsub*4;
        const float4* Wv4 = (const float4*)Wv;
        float4 acc = {0,0,0,0};
        #pragma unroll
        for (int r = 0; r < 4; ++r) {
            float s = ws[OFF_E + c*D + r0 + r];
            float4 v = Wv4[(size_t)(r0 + r) * 256 + j4];
            acc.x += s*v.x; acc.y += s*v.y; acc.z += s*v.z; acc.w += s*v.w;
        }
        gred[rsub][j4] = acc;
        __syncthreads();
        if (rsub == 0) {
            float4 a0 = gred[0][j4], a1 = gred[1][j4], a2 = gred[2][j4], a3 = gred[3][j4];
            float* g = ws + OFF_G + c*8192 + h*D + j4*4;
            atomicAdd(g+0, a0.x+a1.x+a2.x+a3.x);
            atomicAdd(g+1, a0.y+a1.y+a2.y+a3.y);
            atomicAdd(g+2, a0.z+a1.z+a2.z+a3.z);
            atomicAdd(g+3, a0.w+a1.w+a2.w+a3.w);
        }
    } else if (b == 192) {                // ch[h] = qcls_h . bk_h
        __shared__ float red[16];
        int h = t >> 7, d = t & 127;
        float v = ws[OFF_QCLS + h*128 + d] * bk[h*128 + d];
        v = wred(v);
        if (lane == 0) red[w] = v;
        __syncthreads();
        if (t < 8) ws[OFF_CH + t] = red[2*t] + red[2*t+1];
    } else {                              // const_c = Wc.bo + E.bv + bc
        __shared__ float red[32];
        float v0 = Wc[t]*bo[t] + ws[OFF_E + t]*bv[t];
        float v1 = Wc[D + t]*bo[t] + ws[OFF_E + D + t]*bv[t];
        v0 = wred(v0); v1 = wred(v1);
        if (lane == 0) { red[w] = v0; red[16 + w] = v1; }
        __syncthreads();
        if (t == 0) {
            float a0 = 0.f, a1 = 0.f;
            #pragma unroll
            for (int i = 0; i < 16; ++i) { a0 += red[i]; a1 += red[16+i]; }
            ws[OFF_CONST + 0] = a0 + bc[0];
            ws[OFF_CONST + 1] = a1 + bc[1];
        }
    }
}

// ============ K3: single-x-pass scores + exp + u_b  (grid 256 x 512) =========
// LDS stash via global_load_lds; w in VGPRs; DPP reductions; no-max softmax.
__global__ __launch_bounds__(512, 2) void k3(const float* __restrict__ x,
                                             const float* __restrict__ ct,
                                             float* __restrict__ ws) {
    __shared__ float stash[33 * D];       // 132 KB token rows
    __shared__ float pe[33][8];           // e^{score}
    const int b = blockIdx.x, t = threadIdx.x;
    const int w = t >> 6, lane = t & 63;

    // w[h] fragments into registers (128 VGPR): lane l holds f4 {l,l+64,l+128,l+192}
    float4 wreg[8][4];
    const float4* wg4 = (const float4*)(ws + OFF_W);
    #pragma unroll
    for (int h = 0; h < 8; ++h) {
        #pragma unroll
        for (int j = 0; j < 4; ++j)
            wreg[h][j] = wg4[h * 256 + j * 64 + lane];
    }
    float chv[8];
    #pragma unroll
    for (int h = 0; h < 8; ++h) chv[h] = ws[OFF_CH + h];

    // ---- async stash fill: wave w owns tokens [w*4, w*4+4) (+k=32 for b=255,w=7)
    const int ntok_blk = (b == 255) ? 33 : 32;
    const int ntok_w   = (b == 255 && w == 7) ? 5 : 4;
    for (int i = 0; i < ntok_w; ++i) {
        int k = w * 4 + i;
        int s = b * 32 + k;
        const float* row = (s == 0) ? ct : (x + (size_t)(s - 1) * D);
        float* dst = stash + k * D;
        #pragma unroll
        for (int q = 0; q < 4; ++q)
            __builtin_amdgcn_global_load_lds(
                (const __attribute__((address_space(1))) unsigned int*)(row + q * 256 + lane * 4),
                (__attribute__((address_space(3))) unsigned int*)(dst + q * 256),
                16, 0, 0);
    }
    __builtin_amdgcn_s_waitcnt(0x0f70);   // vmcnt(0): own fills done

    // ---- stage A: scores (+exp) for own tokens, from LDS, w from regs ----
    const float scale = 0.08838834764831845f;   // 1/sqrt(128)
    for (int i = 0; i < ntok_w; ++i) {
        int k = w * 4 + i;
        int s = b * 32 + k;
        const float4* tk = (const float4*)(stash + k * D);
        float4 t0 = tk[lane], t1 = tk[64 + lane], t2 = tk[128 + lane], t3 = tk[192 + lane];
        float sc[8];
        #pragma unroll
        for (int h = 0; h < 8; ++h) {
            float4 w0 = wreg[h][0], w1 = wreg[h][1], w2 = wreg[h][2], w3 = wreg[h][3];
            float v = w0.x*t0.x + w0.y*t0.y + w0.z*t0.z + w0.w*t0.w
                    + w1.x*t1.x + w1.y*t1.y + w1.z*t1.z + w1.w*t1.w
                    + w2.x*t2.x + w2.y*t2.y + w2.z*t2.z + w2.w*t2.w
                    + w3.x*t3.x + w3.y*t3.y + w3.z*t3.z + w3.w*t3.w;
            v = wave_total(v);            // DPP, broadcast
            sc[h] = scale * (v + chv[h]);
        }
        if (lane == 0) {
            float4* sct = (float4*)(ws + OFF_SCT);
            sct[s * 2]     = make_float4(sc[0], sc[1], sc[2], sc[3]);
            sct[s * 2 + 1] = make_float4(sc[4], sc[5], sc[6], sc[7]);
            *(float4*)&pe[k][0] = make_float4(__expf(sc[0]), __expf(sc[1]),
                                              __expf(sc[2]), __expf(sc[3]));
            *(float4*)&pe[k][4] = make_float4(__expf(sc[4]), __expf(sc[5]),
                                              __expf(sc[6]), __expf(sc[7]));
        }
    }
    __syncthreads();

    // ---- l_b[h] ----
    if (t < 8) {
        float s = 0.f;
        for (int k = 0; k < ntok_blk; ++k) s += pe[k][t];
        ws[OFF_L + b * 8 + t] = s;
    }

    // ---- stage C: u_b[h][j] = sum_k pe[k][h] * tok[k][j]  (from LDS) ----
    const int f4 = t & 255, half = t >> 8;     // half -> heads 4*half..4*half+3
    const float4* st4 = (const float4*)stash;
    float4 acc0 = {0,0,0,0}, acc1 = {0,0,0,0}, acc2 = {0,0,0,0}, acc3 = {0,0,0,0};
    for (int k = 0; k < ntok_blk; ++k) {
        float4 tv = st4[k * 256 + f4];
        float4 pv = *(const float4*)&pe[k][half * 4];
        acc0.x += pv.x*tv.x; acc0.y += pv.x*tv.y; acc0.z += pv.x*tv.z; acc0.w += pv.x*tv.w;
        acc1.x += pv.y*tv.x; acc1.y += pv.y*tv.y; acc1.z += pv.y*tv.z; acc1.w += pv.y*tv.w;
        acc2.x += pv.z*tv.x; acc2.y += pv.z*tv.y; acc2.z += pv.z*tv.z; acc2.w += pv.z*tv.w;
        acc3.x += pv.w*tv.x; acc3.y += pv.w*tv.y; acc3.z += pv.w*tv.z; acc3.w += pv.w*tv.w;
    }
    float4* ub4 = (float4*)(ws + OFF_UB) + (size_t)b * 2048;
    ub4[(half*4 + 0) * 256 + f4] = acc0;
    ub4[(half*4 + 1) * 256 + f4] = acc1;
    ub4[(half*4 + 2) * 256 + f4] = acc2;
    ub4[(half*4 + 3) * 256 + f4] = acc3;
}

// ============ K4: l-sum + u-reduce + logits + A  (grid 256 x 1024) ===========
__global__ __launch_bounds__(1024) void k4(float* __restrict__ out,
                                           float* __restrict__ ws) {
    __shared__ float red[32][33];
    __shared__ float lp[8][9];
    __shared__ float rlh[8];
    __shared__ float a0r[32], a1r[32];
    const int b = blockIdx.x, t = threadIdx.x;

    // ---- global 1/l_h (redundant per block) ----
    if (t < 64) {
        int h = t & 7, seg = t >> 3;
        float s = 0.f;
        for (int pb = seg * 32; pb < seg * 32 + 32; ++pb) s += ws[OFF_L + pb * 8 + h];
        lp[seg][h] = s;
    }
    __syncthreads();
    if (t < 8) {
        float s = 0.f;
        #pragma unroll
        for (int i = 0; i < 8; ++i) s += lp[i][t];
        rlh[t] = 1.f / s;
    }
    __syncthreads();

    // ---- u-reduce for slice [b*32, b*32+32) over 256 block-partials ----
    {
        int seg = t >> 5, j = t & 31;
        float acc = 0.f;
        for (int pb = seg * 8; pb < seg * 8 + 8; ++pb)
            acc += ws[OFF_UB + (size_t)pb * 8192 + b * 32 + j];
        red[seg][j] = acc;
    }
    __syncthreads();
    if (t < 32) {
        float uval = 0.f;
        #pragma unroll
        for (int i = 0; i < 32; ++i) uval += red[i][t];
        uval *= rlh[b >> 5];              // head = (b*32)/1024
        int jg = b * 32 + t;
        a0r[t] = ws[OFF_G + jg] * uval;
        a1r[t] = ws[OFF_G + 8192 + jg] * uval;
    }
    // ---- A[s] for s in [b*32+1, b*32+32] ----
    if (t >= 64 && t < 96) {
        int s = b * 32 + 1 + (t - 64);    // 1..8192
        const float4* sct = (const float4*)(ws + OFF_SCT);
        float4 sa = sct[s * 2], sb = sct[s * 2 + 1];
        float sum = __expf(sa.x)*rlh[0] + __expf(sa.y)*rlh[1]
                  + __expf(sa.z)*rlh[2] + __expf(sa.w)*rlh[3]
                  + __expf(sb.x)*rlh[4] + __expf(sb.y)*rlh[5]
                  + __expf(sb.z)*rlh[6] + __expf(sb.w)*rlh[7];
        out[6 + s] = sum * 0.125f;
    }
    __syncthreads();
    if (t == 0) {
        float v0 = 0.f, v1 = 0.f;
        #pragma unroll
        for (int i = 0; i < 32; ++i) { v0 += a0r[i]; v1 += a1r[i]; }
        atomicAdd(&ws[OFF_LOGITS + 0], v0);
        atomicAdd(&ws[OFF_LOGITS + 1], v1);
        __threadfence();
        unsigned old = atomicAdd((unsigned*)(ws + OFF_DONE), 1u);
        if (old == 255) {                 // last block finalizes
            float l0 = atomicAdd(&ws[OFF_LOGITS + 0], 0.f) + ws[OFF_CONST + 0];
            float l1 = atomicAdd(&ws[OFF_LOGITS + 1], 0.f) + ws[OFF_CONST + 1];
            float mx = fmaxf(l0, l1);
            float e0 = __expf(l0 - mx), e1 = __expf(l1 - mx);
            float inv = 1.f / (e0 + e1);
            float p0 = e0 * inv, p1 = e1 * inv;
            int am = (p1 > p0) ? 1 : 0;
            out[0] = l0; out[1] = l1;
            out[2] = p0; out[3] = p1;
            out[4] = (float)am;
            out[5] = p0; out[6] = p1;
        }
    }
}

extern "C" void kernel_launch(void* const* d_in, const int* in_sizes, int n_in,
                              void* d_out, int out_size, void* d_ws, size_t ws_size,
                              hipStream_t stream) {
    const float* x  = (const float*)d_in[0];
    const float* ct = (const float*)d_in[1];
    const float* Wq = (const float*)d_in[2];
    const float* bq = (const float*)d_in[3];
    const float* Wk = (const float*)d_in[4];
    const float* bk = (const float*)d_in[5];
    const float* Wv = (const float*)d_in[6];
    const float* bv = (const float*)d_in[7];
    const float* Wo = (const float*)d_in[8];
    const float* bo = (const float*)d_in[9];
    const float* Wc = (const float*)d_in[10];
    const float* bc = (const float*)d_in[11];
    float* out = (float*)d_out;
    float* ws  = (float*)d_ws;

    hipMemsetAsync(d_ws, 0, ZERO_FLTS * sizeof(float), stream);
    k1<<<dim3(1088), dim3(256),  0, stream>>>(Wq, bq, ct, Wc, Wo, ws);
    k2<<<dim3(194),  dim3(1024), 0, stream>>>(Wk, bk, Wv, Wc, bo, bv, bc, ws);
    k3<<<dim3(256),  dim3(512),  0, stream>>>(x, ct, ws);
    k4<<<dim3(256),  dim3(1024), 0, stream>>>(out, ws);
}

// Round 5
// 125.091 us; speedup vs baseline: 2.2655x; 1.0867x over previous
//
#include <hip/hip_runtime.h>
#include <math.h>

#define D 1024
#define NH 8
#define T 8193

// ---- ws float-offsets (no zeroed region, no atomics anywhere) ----
#define OFF_QCLS  0         // 1024
#define OFF_EP    1024      // 8*2048   E-partials [p][c*1024+j]
#define OFF_W     17408     // 8192     [h*1024+j]
#define OFF_G     25600     // 16384    [c*8192 + h*1024 + j]
#define OFF_CH    41984     // 8
#define OFF_CONST 41992     // 2
#define OFF_L     42000     // 256*8    l_b [b*8+h]
#define OFF_PLOG  44048     // 256*16   [b*16 + c*8 + h]
#define OFF_SCT   48144     // 8193*8   pe[s*8+h] = e^{score}

static __device__ __forceinline__ float wred(float v) {
    #pragma unroll
    for (int m = 32; m; m >>= 1) v += __shfl_xor(v, m, 64);
    return v;
}

// DPP wave-64 sum, result broadcast to all lanes via readlane(63). VALU only.
#define DPPADD(v, ctrl) \
    ((v) + __int_as_float(__builtin_amdgcn_update_dpp( \
        0, __float_as_int(v), (ctrl), 0xf, 0xf, true)))

static __device__ __forceinline__ float wave_total(float v) {
    v = DPPADD(v, 0x111);   // row_shr:1
    v = DPPADD(v, 0x112);   // row_shr:2
    v = DPPADD(v, 0x114);   // row_shr:4
    v = DPPADD(v, 0x118);   // row_shr:8
    v = DPPADD(v, 0x142);   // row_bcast:15
    v = DPPADD(v, 0x143);   // row_bcast:31
    return __int_as_float(__builtin_amdgcn_readlane(__float_as_int(v), 63));
}

// ============ K1: qcls (blocks 0..255, 4 rows each) + E-partials (256..287) ==
__global__ __launch_bounds__(1024) void k1(const float* __restrict__ Wq,
                                           const float* __restrict__ bq,
                                           const float* __restrict__ ct,
                                           const float* __restrict__ Wc,
                                           const float* __restrict__ Wo,
                                           float* __restrict__ ws) {
    __shared__ float red[16];
    __shared__ float er[4][2][256];
    const int b = blockIdx.x, t = threadIdx.x;
    const int w = t >> 6, lane = t & 63;
    if (b < 256) {                        // qcls rows 4b..4b+3
        int grp = t >> 8, f4 = t & 255;
        int r = b * 4 + grp;
        const float4* wr = (const float4*)(Wq + (size_t)r * D);
        const float4* cv = (const float4*)ct;
        float4 a = wr[f4], c = cv[f4];
        float v = a.x*c.x + a.y*c.y + a.z*c.z + a.w*c.w;
        v = wred(v);
        if (lane == 0) red[w] = v;
        __syncthreads();
        if (t < 4)
            ws[OFF_QCLS + b*4 + t] = red[4*t]+red[4*t+1]+red[4*t+2]+red[4*t+3] + bq[b*4 + t];
    } else {                              // E-partial p over 128 Wo rows, j-quarter
        int idx = b - 256;                // 0..31
        int p = idx >> 2, jq = idx & 3;
        int layer = t >> 8, jl = t & 255;
        int j = jq * 256 + jl;
        int i0 = p * 128 + layer * 32;
        const float* wo = Wo + (size_t)i0 * D + j;
        float a0 = 0.f, a1 = 0.f;
        #pragma unroll 8
        for (int i = 0; i < 32; ++i) {
            float r = wo[(size_t)i * D];
            a0 += Wc[i0 + i] * r;
            a1 += Wc[D + i0 + i] * r;
        }
        er[layer][0][jl] = a0;
        er[layer][1][jl] = a1;
        __syncthreads();
        if (t < 512) {
            int c = t >> 8, jl2 = t & 255;
            ws[OFF_EP + p*2048 + c*1024 + jq*256 + jl2] =
                er[0][c][jl2] + er[1][c][jl2] + er[2][c][jl2] + er[3][c][jl2];
        }
    }
}

// ============ K2: w (0..31) + G (32..63) + ch (64) + const (65) ==============
__global__ __launch_bounds__(1024) void k2(const float* __restrict__ Wk,
                                           const float* __restrict__ bk,
                                           const float* __restrict__ Wv,
                                           const float* __restrict__ Wc,
                                           const float* __restrict__ bo,
                                           const float* __restrict__ bv,
                                           const float* __restrict__ bc,
                                           float* __restrict__ ws) {
    __shared__ float qh[128];
    __shared__ float el[2][128];
    __shared__ float lr[4][2][256];
    __shared__ float red[32];
    const int b = blockIdx.x, t = threadIdx.x;
    const int w = t >> 6, lane = t & 63;
    if (b < 32) {                         // w[h, j-quarter], 4 d-layers of 32
        int h = b >> 2, jq = b & 3;
        if (t < 128) qh[t] = ws[OFF_QCLS + h*128 + t];
        __syncthreads();
        int layer = t >> 8, jl = t & 255;
        int j = jq * 256 + jl, d0 = layer * 32;
        const float* wk = Wk + (size_t)(h*128 + d0) * D + j;
        float acc = 0.f;
        #pragma unroll 8
        for (int d = 0; d < 32; ++d) acc += qh[d0 + d] * wk[(size_t)d * D];
        lr[layer][0][jl] = acc;
        __syncthreads();
        if (t < 256)
            ws[OFF_W + h*1024 + jq*256 + t] = lr[0][0][t]+lr[1][0][t]+lr[2][0][t]+lr[3][0][t];
    } else if (b < 64) {                  // G[c, h, j-quarter]
        int hb = b - 32, h = hb >> 2, jq = hb & 3;
        if (t < 256) {
            int c = t >> 7, r = t & 127;
            float s = 0.f;
            #pragma unroll
            for (int p = 0; p < 8; ++p) s += ws[OFF_EP + p*2048 + c*1024 + h*128 + r];
            el[c][r] = s;
        }
        __syncthreads();
        int layer = t >> 8, jl = t & 255;
        int j = jq * 256 + jl, r0 = layer * 32;
        const float* wv = Wv + (size_t)(h*128 + r0) * D + j;
        float a0 = 0.f, a1 = 0.f;
        #pragma unroll 8
        for (int r = 0; r < 32; ++r) {
            float xv = wv[(size_t)r * D];
            a0 += el[0][r0 + r] * xv;
            a1 += el[1][r0 + r] * xv;
        }
        lr[layer][0][jl] = a0;
        lr[layer][1][jl] = a1;
        __syncthreads();
        if (t < 512) {
            int c = t >> 8, jl2 = t & 255;
            ws[OFF_G + c*8192 + h*1024 + jq*256 + jl2] =
                lr[0][c][jl2] + lr[1][c][jl2] + lr[2][c][jl2] + lr[3][c][jl2];
        }
    } else if (b == 64) {                 // ch[h] = qcls_h . bk_h
        int h = t >> 7, d = t & 127;
        float v = ws[OFF_QCLS + h*128 + d] * bk[h*128 + d];
        v = wred(v);
        if (lane == 0) red[w] = v;
        __syncthreads();
        if (t < 8) ws[OFF_CH + t] = red[2*t] + red[2*t+1];
    } else {                              // const_c = Wc.bo + E.bv + bc
        float e0 = 0.f, e1 = 0.f;
        #pragma unroll
        for (int p = 0; p < 8; ++p) {
            e0 += ws[OFF_EP + p*2048 + t];
            e1 += ws[OFF_EP + p*2048 + 1024 + t];
        }
        float v0 = Wc[t]*bo[t] + e0*bv[t];
        float v1 = Wc[D + t]*bo[t] + e1*bv[t];
        v0 = wred(v0); v1 = wred(v1);
        if (lane == 0) { red[w] = v0; red[16 + w] = v1; }
        __syncthreads();
        if (t == 0) {
            float a0 = 0.f, a1 = 0.f;
            #pragma unroll
            for (int i = 0; i < 16; ++i) { a0 += red[i]; a1 += red[16 + i]; }
            ws[OFF_CONST + 0] = a0 + bc[0];
            ws[OFF_CONST + 1] = a1 + bc[1];
        }
    }
}

// ============ K3: x single pass: pe + l_b + plog_b  (grid 256 x 512) =========
__global__ __launch_bounds__(512, 2) void k3(const float* __restrict__ x,
                                             const float* __restrict__ ct,
                                             float* __restrict__ ws) {
    __shared__ float stash[33 * D];       // 132 KB token rows
    __shared__ float pe[33][8];
    __shared__ float plred[8][8];
    const int b = blockIdx.x, t = threadIdx.x;
    const int w = t >> 6, lane = t & 63;

    // w fragments in VGPRs: lane l holds float4s {l, l+64, l+128, l+192}
    float4 wreg[8][4];
    const float4* wg4 = (const float4*)(ws + OFF_W);
    #pragma unroll
    for (int h = 0; h < 8; ++h)
        #pragma unroll
        for (int j = 0; j < 4; ++j)
            wreg[h][j] = wg4[h * 256 + j * 64 + lane];
    float chv[8];
    #pragma unroll
    for (int h = 0; h < 8; ++h) chv[h] = ws[OFF_CH + h];

    // async stash fill: wave w owns tokens w*4..w*4+3 (+k=32 for b=255,w=7)
    const int ntok_blk = (b == 255) ? 33 : 32;
    const bool tail = (b == 255 && w == 7);
    const int ntok_w = tail ? 5 : 4;
    for (int i = 0; i < ntok_w; ++i) {
        int k = (i < 4) ? (w * 4 + i) : 32;
        int s = b * 32 + k;
        const float* row = (s == 0) ? ct : (x + (size_t)(s - 1) * D);
        float* dst = stash + k * D;
        #pragma unroll
        for (int q = 0; q < 4; ++q)
            __builtin_amdgcn_global_load_lds(
                (const __attribute__((address_space(1))) unsigned int*)(row + q * 256 + lane * 4),
                (__attribute__((address_space(3))) unsigned int*)(dst + q * 256),
                16, 0, 0);
    }

    const float scale = 0.08838834764831845f;   // 1/sqrt(128)
    auto compute = [&](int k) {
        int s = b * 32 + k;
        const float4* tk = (const float4*)(stash + k * D);
        float4 t0 = tk[lane], t1 = tk[64 + lane], t2 = tk[128 + lane], t3 = tk[192 + lane];
        float pv[8];
        #pragma unroll
        for (int h = 0; h < 8; ++h) {
            float4 w0 = wreg[h][0], w1 = wreg[h][1], w2 = wreg[h][2], w3 = wreg[h][3];
            float v = w0.x*t0.x + w0.y*t0.y + w0.z*t0.z + w0.w*t0.w
                    + w1.x*t1.x + w1.y*t1.y + w1.z*t1.z + w1.w*t1.w
                    + w2.x*t2.x + w2.y*t2.y + w2.z*t2.z + w2.w*t2.w
                    + w3.x*t3.x + w3.y*t3.y + w3.z*t3.z + w3.w*t3.w;
            v = wave_total(v);
            pv[h] = __expf(scale * (v + chv[h]));
        }
        if (lane == 0) {
            float4* sct = (float4*)(ws + OFF_SCT);
            sct[s * 2]     = make_float4(pv[0], pv[1], pv[2], pv[3]);
            sct[s * 2 + 1] = make_float4(pv[4], pv[5], pv[6], pv[7]);
            *(float4*)&pe[k][0] = make_float4(pv[0], pv[1], pv[2], pv[3]);
            *(float4*)&pe[k][4] = make_float4(pv[4], pv[5], pv[6], pv[7]);
        }
    };

    if (!tail) {                          // overlap fetch & compute per token
        __builtin_amdgcn_s_waitcnt(0x0f7c); compute(w*4 + 0);   // vmcnt(12)
        __builtin_amdgcn_s_waitcnt(0x0f78); compute(w*4 + 1);   // vmcnt(8)
        __builtin_amdgcn_s_waitcnt(0x0f74); compute(w*4 + 2);   // vmcnt(4)
        __builtin_amdgcn_s_waitcnt(0x0f70); compute(w*4 + 3);   // vmcnt(0)
    } else {
        __builtin_amdgcn_s_waitcnt(0x0f70);
        for (int i = 0; i < 5; ++i) compute((i < 4) ? (w*4 + i) : 32);
    }
    __syncthreads();

    // l_b[h]
    if (t < 8) {
        float s = 0.f;
        for (int k = 0; k < ntok_blk; ++k) s += pe[k][t];
        ws[OFF_L + b * 8 + t] = s;
    }

    // u_b in registers: thread (half, f4) owns heads 4*half.. , float4 j-slice f4
    const int f4 = t & 255, half = t >> 8;
    const float4* st4 = (const float4*)stash;
    float4 acc0 = {0,0,0,0}, acc1 = {0,0,0,0}, acc2 = {0,0,0,0}, acc3 = {0,0,0,0};
    for (int k = 0; k < ntok_blk; ++k) {
        float4 tv = st4[k * 256 + f4];
        float4 pv = *(const float4*)&pe[k][half * 4];
        acc0.x += pv.x*tv.x; acc0.y += pv.x*tv.y; acc0.z += pv.x*tv.z; acc0.w += pv.x*tv.w;
        acc1.x += pv.y*tv.x; acc1.y += pv.y*tv.y; acc1.z += pv.y*tv.z; acc1.w += pv.y*tv.w;
        acc2.x += pv.z*tv.x; acc2.y += pv.z*tv.y; acc2.z += pv.z*tv.z; acc2.w += pv.z*tv.w;
        acc3.x += pv.w*tv.x; acc3.y += pv.w*tv.y; acc3.z += pv.w*tv.z; acc3.w += pv.w*tv.w;
    }

    // plog_b[c][h] = G[c,h,:] . u_b[h,:]   (G is L2-hot, 64 KB total)
    const float4* G4 = (const float4*)(ws + OFF_G);
    float pl[8];
    #pragma unroll
    for (int c = 0; c < 2; ++c) {
        float4 g0 = G4[c*2048 + (half*4 + 0)*256 + f4];
        float4 g1 = G4[c*2048 + (half*4 + 1)*256 + f4];
        float4 g2 = G4[c*2048 + (half*4 + 2)*256 + f4];
        float4 g3 = G4[c*2048 + (half*4 + 3)*256 + f4];
        pl[c*4+0] = g0.x*acc0.x + g0.y*acc0.y + g0.z*acc0.z + g0.w*acc0.w;
        pl[c*4+1] = g1.x*acc1.x + g1.y*acc1.y + g1.z*acc1.z + g1.w*acc1.w;
        pl[c*4+2] = g2.x*acc2.x + g2.y*acc2.y + g2.z*acc2.z + g2.w*acc2.w;
        pl[c*4+3] = g3.x*acc3.x + g3.y*acc3.y + g3.z*acc3.z + g3.w*acc3.w;
    }
    #pragma unroll
    for (int v = 0; v < 8; ++v) pl[v] = wave_total(pl[v]);
    if (lane == 0)
        #pragma unroll
        for (int v = 0; v < 8; ++v) plred[w][v] = pl[v];
    __syncthreads();
    if (t < 16) {                         // combine 4 waves per half
        int c = t >> 3, hh = t & 7;
        int wb = (hh < 4) ? 0 : 4, vi = c * 4 + (hh & 3);
        ws[OFF_PLOG + b*16 + t] =
            plred[wb][vi] + plred[wb+1][vi] + plred[wb+2][vi] + plred[wb+3][vi];
    }
}

// ============ K4: rlh + A + logits (block 0)  (grid 256 x 256) ===============
__global__ __launch_bounds__(256) void k4(float* __restrict__ out,
                                          float* __restrict__ ws) {
    __shared__ float lp[32][8];
    __shared__ float rlh[8];
    __shared__ float r2[8];
    const int b = blockIdx.x, t = threadIdx.x;

    {   // global 1/l_h (redundant per block)
        int seg = t >> 3, h = t & 7;
        float s = 0.f;
        for (int pb = seg; pb < 256; pb += 32) s += ws[OFF_L + pb*8 + h];
        lp[seg][h] = s;
    }
    __syncthreads();
    if (t < 8) {
        float s = 0.f;
        #pragma unroll
        for (int i = 0; i < 32; ++i) s += lp[i][t];
        rlh[t] = 1.f / s;
    }
    __syncthreads();

    // A[s], s = b*32 + t + 1  (pe already stored in SCT)
    if (t < 32) {
        int s_ = b * 32 + t + 1;
        const float4* sct = (const float4*)(ws + OFF_SCT);
        float4 pa = sct[s_ * 2], pb4 = sct[s_ * 2 + 1];
        float sum = pa.x*rlh[0] + pa.y*rlh[1] + pa.z*rlh[2] + pa.w*rlh[3]
                  + pb4.x*rlh[4] + pb4.y*rlh[5] + pb4.z*rlh[6] + pb4.w*rlh[7];
        out[6 + s_] = sum * 0.125f;
    }

    if (b == 0) {                         // logits + scalar outputs
        float v0 = 0.f, v1 = 0.f;
        for (int idx = t; idx < 4096; idx += 256) {
            float val = ws[OFF_PLOG + idx];
            int rem = idx & 15;
            float z = val * rlh[rem & 7];
            if ((rem >> 3) == 0) v0 += z; else v1 += z;
        }
        v0 = wred(v0); v1 = wred(v1);
        if ((t & 63) == 0) { r2[t >> 6] = v0; r2[4 + (t >> 6)] = v1; }
        __syncthreads();
        if (t == 0) {
            float l0 = r2[0]+r2[1]+r2[2]+r2[3] + ws[OFF_CONST + 0];
            float l1 = r2[4]+r2[5]+r2[6]+r2[7] + ws[OFF_CONST + 1];
            float mx = fmaxf(l0, l1);
            float e0 = __expf(l0 - mx), e1 = __expf(l1 - mx);
            float inv = 1.f / (e0 + e1);
            float p0 = e0 * inv, p1 = e1 * inv;
            int am = (p1 > p0) ? 1 : 0;
            out[0] = l0; out[1] = l1;
            out[2] = p0; out[3] = p1;
            out[4] = (float)am;
            out[5] = p0; out[6] = p1;
        }
    }
}

extern "C" void kernel_launch(void* const* d_in, const int* in_sizes, int n_in,
                              void* d_out, int out_size, void* d_ws, size_t ws_size,
                              hipStream_t stream) {
    const float* x  = (const float*)d_in[0];
    const float* ct = (const float*)d_in[1];
    const float* Wq = (const float*)d_in[2];
    const float* bq = (const float*)d_in[3];
    const float* Wk = (const float*)d_in[4];
    const float* bk = (const float*)d_in[5];
    const float* Wv = (const float*)d_in[6];
    const float* bv = (const float*)d_in[7];
    const float* Wo = (const float*)d_in[8];
    const float* bo = (const float*)d_in[9];
    const float* Wc = (const float*)d_in[10];
    const float* bc = (const float*)d_in[11];
    float* out = (float*)d_out;
    float* ws  = (float*)d_ws;

    k1<<<dim3(288), dim3(1024), 0, stream>>>(Wq, bq, ct, Wc, Wo, ws);
    k2<<<dim3(66),  dim3(1024), 0, stream>>>(Wk, bk, Wv, Wc, bo, bv, bc, ws);
    k3<<<dim3(256), dim3(512),  0, stream>>>(x, ct, ws);
    k4<<<dim3(256), dim3(256),  0, stream>>>(out, ws);
}